// Round 1
// baseline (5711.516 us; speedup 1.0000x reference)
//
#include <hip/hip_runtime.h>
#include <math.h>

#define NN 100000
#define EE 3200000
#define FF 128
#define HH 6
#define CC 10
#define GG 512

// ---------------- degree / dinv ----------------
__global__ __launch_bounds__(256) void k_degree(const int* __restrict__ dst,
                                                float* __restrict__ deg) {
    int e = blockIdx.x * 256 + threadIdx.x;
    if (e < EE) atomicAdd(&deg[dst[e]], 1.0f);
}

__global__ __launch_bounds__(256) void k_dinv(float* __restrict__ deg) {
    int i = blockIdx.x * 256 + threadIdx.x;
    if (i < NN) deg[i] = rsqrtf(deg[i] + 1.0f);  // +1 = self-loop; deg>=1 always
}

// ---------------- x @ W1  (N x 128 -> N x 6), one wave per node ----------------
__global__ __launch_bounds__(256) void k_xw1(const float* __restrict__ x,
                                             const float* __restrict__ W,
                                             float* __restrict__ out) {
    __shared__ float sW[FF * HH];
    for (int i = threadIdx.x; i < FF * HH; i += 256) sW[i] = W[i];
    __syncthreads();
    int wid  = (blockIdx.x * 256 + threadIdx.x) >> 6;
    int lane = threadIdx.x & 63;
    if (wid >= NN) return;
    const float* xr = x + (size_t)wid * FF;
    float a0 = xr[lane], a1 = xr[lane + 64];   // coalesced across the wave
    float acc[HH];
#pragma unroll
    for (int c = 0; c < HH; ++c)
        acc[c] = a0 * sW[lane * HH + c] + a1 * sW[(lane + 64) * HH + c];
#pragma unroll
    for (int off = 32; off >= 1; off >>= 1)
#pragma unroll
        for (int c = 0; c < HH; ++c) acc[c] += __shfl_down(acc[c], off, 64);
    if (lane == 0) {
#pragma unroll
        for (int c = 0; c < HH; ++c) out[(size_t)wid * HH + c] = acc[c];
    }
}

// ---------------- tiny dense mm: h (N x HIN) @ W (HIN x HOUT) ----------------
template <int HIN, int HOUT>
__global__ __launch_bounds__(256) void k_mm_small(const float* __restrict__ h,
                                                  const float* __restrict__ W,
                                                  float* __restrict__ out) {
    __shared__ float sW[HIN * HOUT];
    if (threadIdx.x < HIN * HOUT) sW[threadIdx.x] = W[threadIdx.x];
    __syncthreads();
    int i = blockIdx.x * 256 + threadIdx.x;
    if (i >= NN) return;
    float a[HIN];
#pragma unroll
    for (int k = 0; k < HIN; ++k) a[k] = h[(size_t)i * HIN + k];
#pragma unroll
    for (int c = 0; c < HOUT; ++c) {
        float s = 0.f;
#pragma unroll
        for (int k = 0; k < HIN; ++k) s += a[k] * sW[k * HOUT + c];
        out[(size_t)i * HOUT + c] = s;
    }
}

// ---------------- edge scatter: agg[dst] += dinv[s]*dinv[d] * hw[src] ----------------
template <int H>
__global__ __launch_bounds__(256) void k_scatter(const int* __restrict__ src,
                                                 const int* __restrict__ dst,
                                                 const float* __restrict__ dinv,
                                                 const float* __restrict__ hw,
                                                 float* __restrict__ agg) {
    int e = blockIdx.x * 256 + threadIdx.x;
    if (e >= EE) return;
    int s = src[e], d = dst[e];
    float nrm = dinv[s] * dinv[d];
#pragma unroll
    for (int c = 0; c < H; ++c)
        atomicAdd(&agg[(size_t)d * H + c], nrm * hw[(size_t)s * H + c]);
}

// ---------------- finalize: agg += dinv^2 * hw (self-loop) + b, relu ----------------
template <int H>
__global__ __launch_bounds__(256) void k_finalize(const float* __restrict__ dinv,
                                                  const float* __restrict__ hw,
                                                  const float* __restrict__ b,
                                                  float* __restrict__ agg) {
    int i = blockIdx.x * 256 + threadIdx.x;
    if (i >= NN) return;
    float di = dinv[i], sl = di * di;
#pragma unroll
    for (int c = 0; c < H; ++c) {
        float v = agg[(size_t)i * H + c] + sl * hw[(size_t)i * H + c] + b[c];
        agg[(size_t)i * H + c] = fmaxf(v, 0.f);
    }
}

// ---------------- graph boundaries via binary search (batch is sorted) ----------------
__global__ __launch_bounds__(256) void k_bounds(const int* __restrict__ batch,
                                                int* __restrict__ bounds) {
    int g = blockIdx.x * 256 + threadIdx.x;
    if (g > GG) return;
    int lo = 0, hi = NN;
    while (lo < hi) {
        int mid = (lo + hi) >> 1;
        if (batch[mid] < g) lo = mid + 1; else hi = mid;
    }
    bounds[g] = lo;
}

// ---------------- mean-pool + log_softmax, one block per graph ----------------
__global__ __launch_bounds__(256) void k_pool(const float* __restrict__ h,
                                              const int* __restrict__ bounds,
                                              float* __restrict__ out) {
    int g = blockIdx.x;
    int s = bounds[g], e = bounds[g + 1];
    float acc[CC];
#pragma unroll
    for (int c = 0; c < CC; ++c) acc[c] = 0.f;
    for (int i = s + threadIdx.x; i < e; i += 256) {
#pragma unroll
        for (int c = 0; c < CC; ++c) acc[c] += h[(size_t)i * CC + c];
    }
#pragma unroll
    for (int off = 32; off >= 1; off >>= 1)
#pragma unroll
        for (int c = 0; c < CC; ++c) acc[c] += __shfl_down(acc[c], off, 64);
    __shared__ float sacc[4][CC];
    int wv = threadIdx.x >> 6, lane = threadIdx.x & 63;
    if (lane == 0) {
#pragma unroll
        for (int c = 0; c < CC; ++c) sacc[wv][c] = acc[c];
    }
    __syncthreads();
    if (threadIdx.x == 0) {
        float cnt = fmaxf((float)(e - s), 1.0f);
        float tot[CC];
        float m = -1e30f;
#pragma unroll
        for (int c = 0; c < CC; ++c) {
            tot[c] = (sacc[0][c] + sacc[1][c] + sacc[2][c] + sacc[3][c]) / cnt;
            m = fmaxf(m, tot[c]);
        }
        float ssum = 0.f;
#pragma unroll
        for (int c = 0; c < CC; ++c) ssum += expf(tot[c] - m);
        float lse = logf(ssum) + m;
#pragma unroll
        for (int c = 0; c < CC; ++c) out[(size_t)g * CC + c] = tot[c] - lse;
    }
}

extern "C" void kernel_launch(void* const* d_in, const int* in_sizes, int n_in,
                              void* d_out, int out_size, void* d_ws, size_t ws_size,
                              hipStream_t stream) {
    const float* x     = (const float*)d_in[0];
    const int*   ei    = (const int*)d_in[1];
    const int*   batch = (const int*)d_in[2];
    const float* W1 = (const float*)d_in[3];
    const float* b1 = (const float*)d_in[4];
    const float* W2 = (const float*)d_in[5];
    const float* b2 = (const float*)d_in[6];
    const float* W3 = (const float*)d_in[7];
    const float* b3 = (const float*)d_in[8];
    const float* W4 = (const float*)d_in[9];
    const float* b4 = (const float*)d_in[10];
    const float* Wf = (const float*)d_in[11];
    const float* bf = (const float*)d_in[12];
    float* out = (float*)d_out;

    const int* src = ei;
    const int* dst = ei + EE;

    // workspace layout (floats): dinv[N] | bufX[N*10] | bufY[N*10] | bounds[G+1] (int)
    float* w    = (float*)d_ws;
    float* dinv = w;
    float* bufX = w + 100352;           // N rounded up
    float* bufY = bufX + 1000448;       // N*10 rounded up
    int*   bounds = (int*)(bufY + 1000448);

    const int EB = (EE + 255) / 256;    // 12500
    const int NB = (NN + 255) / 256;    // 391

    // degree -> dinv
    hipMemsetAsync(dinv, 0, NN * sizeof(float), stream);
    k_degree<<<EB, 256, 0, stream>>>(dst, dinv);
    k_dinv<<<NB, 256, 0, stream>>>(dinv);

    // layer 1: F=128 -> 6
    k_xw1<<<NN / 4, 256, 0, stream>>>(x, W1, bufX);
    hipMemsetAsync(bufY, 0, NN * HH * sizeof(float), stream);
    k_scatter<HH><<<EB, 256, 0, stream>>>(src, dst, dinv, bufX, bufY);
    k_finalize<HH><<<NB, 256, 0, stream>>>(dinv, bufX, b1, bufY);

    // layers 2-4: 6 -> 6
    const float* Ws[3] = {W2, W3, W4};
    const float* bs[3] = {b2, b3, b4};
    for (int l = 0; l < 3; ++l) {
        k_mm_small<HH, HH><<<NB, 256, 0, stream>>>(bufY, Ws[l], bufX);
        hipMemsetAsync(bufY, 0, NN * HH * sizeof(float), stream);
        k_scatter<HH><<<EB, 256, 0, stream>>>(src, dst, dinv, bufX, bufY);
        k_finalize<HH><<<NB, 256, 0, stream>>>(dinv, bufX, bs[l], bufY);
    }

    // layer 5: 6 -> 10
    k_mm_small<HH, CC><<<NB, 256, 0, stream>>>(bufY, Wf, bufX);
    hipMemsetAsync(bufY, 0, NN * CC * sizeof(float), stream);
    k_scatter<CC><<<EB, 256, 0, stream>>>(src, dst, dinv, bufX, bufY);
    k_finalize<CC><<<NB, 256, 0, stream>>>(dinv, bufX, bf, bufY);

    // pool + log_softmax
    k_bounds<<<3, 256, 0, stream>>>(batch, bounds);
    k_pool<<<GG, 256, 0, stream>>>(bufY, bounds, out);
}

// Round 2
// 742.156 us; speedup vs baseline: 7.6958x; 7.6958x over previous
//
#include <hip/hip_runtime.h>
#include <math.h>

#define NN 100000
#define EE 3200000
#define FF 128
#define HH 6
#define CC 10
#define GG 512

// ================= CSR build =================
__global__ __launch_bounds__(256) void k_hist(const int* __restrict__ dst,
                                              int* __restrict__ counts) {
    int e = blockIdx.x * 256 + threadIdx.x;
    if (e < EE) atomicAdd(&counts[dst[e]], 1);
}

__global__ __launch_bounds__(256) void k_dinv(const int* __restrict__ counts,
                                              float* __restrict__ dinv) {
    int i = blockIdx.x * 256 + threadIdx.x;
    if (i < NN) dinv[i] = rsqrtf((float)counts[i] + 1.0f);  // +1 self-loop
}

__global__ __launch_bounds__(256) void k_blocksum(const int* __restrict__ counts,
                                                  int* __restrict__ partials) {
    __shared__ int s[256];
    int i = blockIdx.x * 256 + threadIdx.x;
    s[threadIdx.x] = (i < NN) ? counts[i] : 0;
    __syncthreads();
    for (int off = 128; off >= 1; off >>= 1) {
        if (threadIdx.x < off) s[threadIdx.x] += s[threadIdx.x + off];
        __syncthreads();
    }
    if (threadIdx.x == 0) partials[blockIdx.x] = s[0];
}

__global__ __launch_bounds__(512) void k_scanpart(int* __restrict__ partials, int nb) {
    __shared__ int s[512];
    int t = threadIdx.x;
    s[t] = (t < nb) ? partials[t] : 0;
    __syncthreads();
    for (int off = 1; off < 512; off <<= 1) {
        int v = (t >= off) ? s[t - off] : 0;
        __syncthreads();
        s[t] += v;
        __syncthreads();
    }
    int excl = (t > 0) ? s[t - 1] : 0;
    if (t < nb) partials[t] = excl;
}

__global__ __launch_bounds__(256) void k_writeptr(const int* __restrict__ counts,
                                                  const int* __restrict__ partials,
                                                  int* __restrict__ rowptr,
                                                  int* __restrict__ cursor) {
    __shared__ int s[256];
    int t = threadIdx.x;
    int i = blockIdx.x * 256 + t;
    int c = (i < NN) ? counts[i] : 0;
    s[t] = c;
    __syncthreads();
    for (int off = 1; off < 256; off <<= 1) {
        int v = (t >= off) ? s[t - off] : 0;
        __syncthreads();
        s[t] += v;
        __syncthreads();
    }
    int excl = partials[blockIdx.x] + s[t] - c;
    if (i < NN) { rowptr[i] = excl; cursor[i] = excl; }
}

__global__ __launch_bounds__(256) void k_fill(const int* __restrict__ src,
                                              const int* __restrict__ dst,
                                              int* __restrict__ cursor,
                                              int* __restrict__ csr) {
    int e = blockIdx.x * 256 + threadIdx.x;
    if (e >= EE) return;
    int d = dst[e];
    int pos = atomicAdd(&cursor[d], 1);
    csr[pos] = src[e];
}

// ================= layer 1: hs = dinv * (x @ W1), padded to 8 =================
__global__ __launch_bounds__(256) void k_xw1(const float* __restrict__ x,
                                             const float* __restrict__ W,
                                             const float* __restrict__ dinv,
                                             float* __restrict__ hs) {
    __shared__ float sW[FF * HH];
    for (int i = threadIdx.x; i < FF * HH; i += 256) sW[i] = W[i];
    __syncthreads();
    int wid  = (blockIdx.x * 256 + threadIdx.x) >> 6;
    int lane = threadIdx.x & 63;
    if (wid >= NN) return;
    const float* xr = x + (size_t)wid * FF;
    float a0 = xr[lane], a1 = xr[lane + 64];
    float acc[HH];
#pragma unroll
    for (int c = 0; c < HH; ++c)
        acc[c] = a0 * sW[lane * HH + c] + a1 * sW[(lane + 64) * HH + c];
#pragma unroll
    for (int off = 32; off >= 1; off >>= 1)
#pragma unroll
        for (int c = 0; c < HH; ++c) acc[c] += __shfl_down(acc[c], off, 64);
    if (lane == 0) {
        float di = dinv[wid];
        float* o = hs + (size_t)wid * 8;
#pragma unroll
        for (int c = 0; c < HH; ++c) o[c] = di * acc[c];
        o[6] = 0.f; o[7] = 0.f;
    }
}

// ===== tiny mm: hs = dinv * (h @ W); h padded HPI, out padded HPO, pads=0 =====
template <int HIN, int HPI, int HOUT, int HPO>
__global__ __launch_bounds__(256) void k_mm(const float* __restrict__ h,
                                            const float* __restrict__ W,
                                            const float* __restrict__ dinv,
                                            float* __restrict__ hs) {
    __shared__ float sW[HIN * HOUT];
    if (threadIdx.x < HIN * HOUT) sW[threadIdx.x] = W[threadIdx.x];
    __syncthreads();
    int i = blockIdx.x * 256 + threadIdx.x;
    if (i >= NN) return;
    float a[HIN];
    const float4* hp = (const float4*)(h + (size_t)i * HPI);
    float4 v0 = hp[0], v1 = hp[1];
    a[0] = v0.x; a[1] = v0.y; a[2] = v0.z; a[3] = v0.w; a[4] = v1.x; a[5] = v1.y;
    float di = dinv[i];
    float* o = hs + (size_t)i * HPO;
#pragma unroll
    for (int c = 0; c < HPO; ++c) {
        if (c < HOUT) {
            float s = 0.f;
#pragma unroll
            for (int k = 0; k < HIN; ++k) s += a[k] * sW[k * HOUT + c];
            o[c] = di * s;
        } else {
            o[c] = 0.f;
        }
    }
}

// ===== gather: out[i] = relu(dinv[i]*(sum_{s in N(i)} hs[s] + hs[i]) + b) =====
template <int H, int HP>
__global__ __launch_bounds__(256) void k_gather(const int* __restrict__ rowptr,
                                                const int* __restrict__ counts,
                                                const int* __restrict__ csr,
                                                const float* __restrict__ dinv,
                                                const float* __restrict__ hs,
                                                const float* __restrict__ b,
                                                float* __restrict__ out) {
    int i = blockIdx.x * 256 + threadIdx.x;
    if (i >= NN) return;
    int st = rowptr[i], cnt = counts[i];
    float acc[HP];
    const float4* self = (const float4*)(hs + (size_t)i * HP);
#pragma unroll
    for (int q = 0; q < HP / 4; ++q) {
        float4 v = self[q];
        acc[4 * q] = v.x; acc[4 * q + 1] = v.y; acc[4 * q + 2] = v.z; acc[4 * q + 3] = v.w;
    }
    for (int j = st; j < st + cnt; ++j) {
        int s = csr[j];
        const float4* p = (const float4*)(hs + (size_t)s * HP);
#pragma unroll
        for (int q = 0; q < HP / 4; ++q) {
            float4 v = p[q];
            acc[4 * q] += v.x; acc[4 * q + 1] += v.y; acc[4 * q + 2] += v.z; acc[4 * q + 3] += v.w;
        }
    }
    float di = dinv[i];
    float* o = out + (size_t)i * HP;
#pragma unroll
    for (int c = 0; c < HP; ++c) {
        float v = di * acc[c] + ((c < H) ? b[c] : 0.f);
        o[c] = (c < H) ? fmaxf(v, 0.f) : 0.f;
    }
}

// ================= pool =================
__global__ __launch_bounds__(256) void k_bounds(const int* __restrict__ batch,
                                                int* __restrict__ bounds) {
    int g = blockIdx.x * 256 + threadIdx.x;
    if (g > GG) return;
    int lo = 0, hi = NN;
    while (lo < hi) {
        int mid = (lo + hi) >> 1;
        if (batch[mid] < g) lo = mid + 1; else hi = mid;
    }
    bounds[g] = lo;
}

__global__ __launch_bounds__(256) void k_pool(const float* __restrict__ h,
                                              const int* __restrict__ bounds,
                                              float* __restrict__ out) {
    int g = blockIdx.x;
    int s = bounds[g], e = bounds[g + 1];
    float acc[CC];
#pragma unroll
    for (int c = 0; c < CC; ++c) acc[c] = 0.f;
    for (int i = s + threadIdx.x; i < e; i += 256) {
#pragma unroll
        for (int c = 0; c < CC; ++c) acc[c] += h[(size_t)i * 12 + c];
    }
#pragma unroll
    for (int off = 32; off >= 1; off >>= 1)
#pragma unroll
        for (int c = 0; c < CC; ++c) acc[c] += __shfl_down(acc[c], off, 64);
    __shared__ float sacc[4][CC];
    int wv = threadIdx.x >> 6, lane = threadIdx.x & 63;
    if (lane == 0) {
#pragma unroll
        for (int c = 0; c < CC; ++c) sacc[wv][c] = acc[c];
    }
    __syncthreads();
    if (threadIdx.x == 0) {
        float cnt = fmaxf((float)(e - s), 1.0f);
        float tot[CC];
        float m = -1e30f;
#pragma unroll
        for (int c = 0; c < CC; ++c) {
            tot[c] = (sacc[0][c] + sacc[1][c] + sacc[2][c] + sacc[3][c]) / cnt;
            m = fmaxf(m, tot[c]);
        }
        float ssum = 0.f;
#pragma unroll
        for (int c = 0; c < CC; ++c) ssum += expf(tot[c] - m);
        float lse = logf(ssum) + m;
#pragma unroll
        for (int c = 0; c < CC; ++c) out[(size_t)g * CC + c] = tot[c] - lse;
    }
}

extern "C" void kernel_launch(void* const* d_in, const int* in_sizes, int n_in,
                              void* d_out, int out_size, void* d_ws, size_t ws_size,
                              hipStream_t stream) {
    const float* x     = (const float*)d_in[0];
    const int*   ei    = (const int*)d_in[1];
    const int*   batch = (const int*)d_in[2];
    const float* W1 = (const float*)d_in[3];
    const float* b1 = (const float*)d_in[4];
    const float* W2 = (const float*)d_in[5];
    const float* b2 = (const float*)d_in[6];
    const float* W3 = (const float*)d_in[7];
    const float* b3 = (const float*)d_in[8];
    const float* W4 = (const float*)d_in[9];
    const float* b4 = (const float*)d_in[10];
    const float* Wf = (const float*)d_in[11];
    const float* bf = (const float*)d_in[12];
    float* out = (float*)d_out;

    const int* src = ei;
    const int* dst = ei + EE;

    // -------- workspace layout (4B units) --------
    float* w    = (float*)d_ws;
    float* dinv = w;                        // [100352]
    float* bufA = w + 100352;               // [1200128]  N*12 padded (hs)
    float* bufB = bufA + 1200128;           // [1200128]  N*12 padded (h out)
    int* ibase   = (int*)(bufB + 1200128);
    int* rowptr  = ibase;                   // [100352]
    int* counts  = rowptr + 100352;         // [100352]
    int* cursor  = counts + 100352;         // [100352]
    int* csr     = cursor + 100352;         // [3200000]
    int* partials= csr + 3200000;           // [512]
    int* bounds  = partials + 512;          // [513]

    const int EB = (EE + 255) / 256;        // 12500
    const int NB = (NN + 255) / 256;        // 391

    // -------- CSR build (once; reused by all 5 layers) --------
    hipMemsetAsync(counts, 0, NN * sizeof(int), stream);
    k_hist<<<EB, 256, 0, stream>>>(dst, counts);
    k_dinv<<<NB, 256, 0, stream>>>(counts, dinv);
    k_blocksum<<<NB, 256, 0, stream>>>(counts, partials);
    k_scanpart<<<1, 512, 0, stream>>>(partials, NB);
    k_writeptr<<<NB, 256, 0, stream>>>(counts, partials, rowptr, cursor);
    k_fill<<<EB, 256, 0, stream>>>(src, dst, cursor, csr);

    // -------- layer 1: F=128 -> 6 --------
    k_xw1<<<NN / 4, 256, 0, stream>>>(x, W1, dinv, bufA);
    k_gather<HH, 8><<<NB, 256, 0, stream>>>(rowptr, counts, csr, dinv, bufA, b1, bufB);

    // -------- layers 2-4: 6 -> 6 --------
    const float* Ws[3] = {W2, W3, W4};
    const float* bs[3] = {b2, b3, b4};
    for (int l = 0; l < 3; ++l) {
        k_mm<HH, 8, HH, 8><<<NB, 256, 0, stream>>>(bufB, Ws[l], dinv, bufA);
        k_gather<HH, 8><<<NB, 256, 0, stream>>>(rowptr, counts, csr, dinv, bufA, bs[l], bufB);
    }

    // -------- layer 5: 6 -> 10 (padded 12) --------
    k_mm<HH, 8, CC, 12><<<NB, 256, 0, stream>>>(bufB, Wf, dinv, bufA);
    k_gather<CC, 12><<<NB, 256, 0, stream>>>(rowptr, counts, csr, dinv, bufA, bf, bufB);

    // -------- pool + log_softmax --------
    k_bounds<<<3, 256, 0, stream>>>(batch, bounds);
    k_pool<<<GG, 256, 0, stream>>>(bufB, bounds, out);
}

// Round 3
// 364.977 us; speedup vs baseline: 15.6490x; 2.0334x over previous
//
#include <hip/hip_runtime.h>
#include <math.h>

#define NN 100000
#define EE 3200000
#define FF 128
#define HH 6
#define CC 10
#define GG 512
#define NBUCK 196          // ceil(NN / 512); bucket = dst >> 9

// ========== pass 1: per-bucket edge histogram ==========
__global__ __launch_bounds__(256) void k_phist(const int* __restrict__ dst,
                                               int* __restrict__ bhist) {
    __shared__ int h[NBUCK];
    int t = threadIdx.x;
    for (int i = t; i < NBUCK; i += 256) h[i] = 0;
    __syncthreads();
    int base = blockIdx.x * 8192;
    for (int k = 0; k < 32; ++k) {
        int e = base + (k << 8) + t;
        if (e < EE) atomicAdd(&h[dst[e] >> 9], 1);
    }
    __syncthreads();
    for (int i = t; i < NBUCK; i += 256)
        if (h[i]) atomicAdd(&bhist[i], h[i]);
}

// ========== pass 2: exclusive scan of 196 bucket counts (1 block) ==========
__global__ __launch_bounds__(256) void k_scanb(const int* __restrict__ bhist,
                                               int* __restrict__ bbase,
                                               int* __restrict__ gcur) {
    __shared__ int s[256];
    int t = threadIdx.x;
    int v = (t < NBUCK) ? bhist[t] : 0;
    s[t] = v;
    __syncthreads();
    for (int off = 1; off < 256; off <<= 1) {
        int u = (t >= off) ? s[t - off] : 0;
        __syncthreads();
        s[t] += u;
        __syncthreads();
    }
    int excl = s[t] - v;
    if (t < NBUCK) { bbase[t] = excl; gcur[t] = excl; }
    if (t == 0) bbase[NBUCK] = EE;
}

// ========== pass 3: partition packed edges into bucket-contiguous runs ==========
__global__ __launch_bounds__(256) void k_partition(const int* __restrict__ src,
                                                   const int* __restrict__ dst,
                                                   int* __restrict__ gcur,
                                                   int* __restrict__ part) {
    __shared__ int lcnt[NBUCK], lbase[NBUCK], lpos[NBUCK];
    int t = threadIdx.x;
    for (int i = t; i < NBUCK; i += 256) { lcnt[i] = 0; lpos[i] = 0; }
    __syncthreads();
    int base = blockIdx.x * 8192;
    for (int k = 0; k < 32; ++k) {
        int e = base + (k << 8) + t;
        if (e < EE) atomicAdd(&lcnt[dst[e] >> 9], 1);
    }
    __syncthreads();
    for (int i = t; i < NBUCK; i += 256)
        lbase[i] = lcnt[i] ? atomicAdd(&gcur[i], lcnt[i]) : 0;
    __syncthreads();
    for (int k = 0; k < 32; ++k) {
        int e = base + (k << 8) + t;
        if (e < EE) {
            int d = dst[e], bkt = d >> 9;
            int r = atomicAdd(&lpos[bkt], 1);
            part[lbase[bkt] + r] = (src[e] << 9) | (d & 511);
        }
    }
}

// ========== pass 4: per-bucket counting sort -> csr, rowptr, counts, dinv ==========
__global__ __launch_bounds__(512) void k_bucketfill(const int* __restrict__ bbase,
                                                    const int* __restrict__ part,
                                                    int* __restrict__ csr,
                                                    int* __restrict__ rowptr,
                                                    int* __restrict__ counts,
                                                    float* __restrict__ dinv) {
    __shared__ int cnt[512], scn[512], cur[512];
    int t = threadIdx.x;
    int b = blockIdx.x;
    int nbase = b << 9;
    int ebase = bbase[b], ecount = bbase[b + 1] - ebase;
    cnt[t] = 0;
    __syncthreads();
    for (int j = t; j < ecount; j += 512)
        atomicAdd(&cnt[part[ebase + j] & 511], 1);
    __syncthreads();
    int c = cnt[t];
    scn[t] = c;
    __syncthreads();
    for (int off = 1; off < 512; off <<= 1) {
        int u = (t >= off) ? scn[t - off] : 0;
        __syncthreads();
        scn[t] += u;
        __syncthreads();
    }
    int rp = ebase + scn[t] - c;   // exclusive
    int node = nbase + t;
    if (node < NN) {
        rowptr[node] = rp;
        counts[node] = c;
        dinv[node] = rsqrtf((float)c + 1.0f);
    }
    cur[t] = rp;
    __syncthreads();
    for (int j = t; j < ecount; j += 512) {
        int p = part[ebase + j];
        int pos = atomicAdd(&cur[p & 511], 1);
        csr[pos] = p >> 9;
    }
}

// ========== layer 1: hs = dinv * (x @ W1), padded to 8 ==========
__global__ __launch_bounds__(256) void k_xw1(const float* __restrict__ x,
                                             const float* __restrict__ W,
                                             const float* __restrict__ dinv,
                                             float* __restrict__ hs) {
    __shared__ float sW[FF * HH];
    for (int i = threadIdx.x; i < FF * HH; i += 256) sW[i] = W[i];
    __syncthreads();
    int wid  = (blockIdx.x * 256 + threadIdx.x) >> 6;
    int lane = threadIdx.x & 63;
    if (wid >= NN) return;
    const float* xr = x + (size_t)wid * FF;
    float a0 = xr[lane], a1 = xr[lane + 64];
    float acc[HH];
#pragma unroll
    for (int c = 0; c < HH; ++c)
        acc[c] = a0 * sW[lane * HH + c] + a1 * sW[(lane + 64) * HH + c];
#pragma unroll
    for (int off = 32; off >= 1; off >>= 1)
#pragma unroll
        for (int c = 0; c < HH; ++c) acc[c] += __shfl_down(acc[c], off, 64);
    if (lane == 0) {
        float di = dinv[wid];
        float* o = hs + (size_t)wid * 8;
#pragma unroll
        for (int c = 0; c < HH; ++c) o[c] = di * acc[c];
        o[6] = 0.f; o[7] = 0.f;
    }
}

// ===== fused gather+next-mm: h = relu(dinv*(sum nbr hs + hs_self) + b);
//       out = dinv * (h @ Wn), out padded HPO =====
template <int HON, int HPO>
__global__ __launch_bounds__(256) void k_gf(const int* __restrict__ rowptr,
                                            const int* __restrict__ counts,
                                            const int* __restrict__ csr,
                                            const float* __restrict__ dinv,
                                            const float* __restrict__ hs,
                                            const float* __restrict__ bias,
                                            const float* __restrict__ Wn,
                                            float* __restrict__ outn) {
    __shared__ float sW[HH * HON];
    if (threadIdx.x < HH * HON) sW[threadIdx.x] = Wn[threadIdx.x];
    __syncthreads();
    int i = blockIdx.x * 256 + threadIdx.x;
    if (i >= NN) return;
    float rb[HH];
#pragma unroll
    for (int c = 0; c < HH; ++c) rb[c] = bias[c];
    int st = rowptr[i], en = st + counts[i];
    const float4* sp = (const float4*)(hs + (size_t)i * 8);
    float4 A = sp[0], B = sp[1];
    float a0 = A.x, a1 = A.y, a2 = A.z, a3 = A.w, a4 = B.x, a5 = B.y;
    int j = st;
    for (; j + 4 <= en; j += 4) {
        int s0 = csr[j], s1 = csr[j + 1], s2 = csr[j + 2], s3 = csr[j + 3];
        const float4* p0 = (const float4*)(hs + (size_t)s0 * 8);
        const float4* p1 = (const float4*)(hs + (size_t)s1 * 8);
        const float4* p2 = (const float4*)(hs + (size_t)s2 * 8);
        const float4* p3 = (const float4*)(hs + (size_t)s3 * 8);
        float4 x0 = p0[0], y0 = p0[1];
        float4 x1 = p1[0], y1 = p1[1];
        float4 x2 = p2[0], y2 = p2[1];
        float4 x3 = p3[0], y3 = p3[1];
        a0 += x0.x + x1.x + x2.x + x3.x;
        a1 += x0.y + x1.y + x2.y + x3.y;
        a2 += x0.z + x1.z + x2.z + x3.z;
        a3 += x0.w + x1.w + x2.w + x3.w;
        a4 += y0.x + y1.x + y2.x + y3.x;
        a5 += y0.y + y1.y + y2.y + y3.y;
    }
    for (; j < en; ++j) {
        int s = csr[j];
        const float4* p = (const float4*)(hs + (size_t)s * 8);
        float4 xx = p[0], yy = p[1];
        a0 += xx.x; a1 += xx.y; a2 += xx.z; a3 += xx.w; a4 += yy.x; a5 += yy.y;
    }
    float di = dinv[i];
    float h[HH];
    h[0] = fmaxf(di * a0 + rb[0], 0.f);
    h[1] = fmaxf(di * a1 + rb[1], 0.f);
    h[2] = fmaxf(di * a2 + rb[2], 0.f);
    h[3] = fmaxf(di * a3 + rb[3], 0.f);
    h[4] = fmaxf(di * a4 + rb[4], 0.f);
    h[5] = fmaxf(di * a5 + rb[5], 0.f);
    float* o = outn + (size_t)i * HPO;
#pragma unroll
    for (int c = 0; c < HPO; ++c) {
        if (c < HON) {
            float s = 0.f;
#pragma unroll
            for (int k = 0; k < HH; ++k) s += h[k] * sW[k * HON + c];
            o[c] = di * s;
        } else {
            o[c] = 0.f;
        }
    }
}

// ===== last gather (layer 5): h5 = relu(dinv*(sum hs5 + self) + bf), 12-pad =====
__global__ __launch_bounds__(256) void k_glast(const int* __restrict__ rowptr,
                                               const int* __restrict__ counts,
                                               const int* __restrict__ csr,
                                               const float* __restrict__ dinv,
                                               const float* __restrict__ hs,
                                               const float* __restrict__ bias,
                                               float* __restrict__ out) {
    int i = blockIdx.x * 256 + threadIdx.x;
    if (i >= NN) return;
    int st = rowptr[i], en = st + counts[i];
    float acc[12];
    const float4* sp = (const float4*)(hs + (size_t)i * 12);
#pragma unroll
    for (int q = 0; q < 3; ++q) {
        float4 v = sp[q];
        acc[4 * q] = v.x; acc[4 * q + 1] = v.y; acc[4 * q + 2] = v.z; acc[4 * q + 3] = v.w;
    }
    int j = st;
    for (; j + 2 <= en; j += 2) {
        int s0 = csr[j], s1 = csr[j + 1];
        const float4* p0 = (const float4*)(hs + (size_t)s0 * 12);
        const float4* p1 = (const float4*)(hs + (size_t)s1 * 12);
#pragma unroll
        for (int q = 0; q < 3; ++q) {
            float4 v0 = p0[q], v1 = p1[q];
            acc[4 * q] += v0.x + v1.x; acc[4 * q + 1] += v0.y + v1.y;
            acc[4 * q + 2] += v0.z + v1.z; acc[4 * q + 3] += v0.w + v1.w;
        }
    }
    for (; j < en; ++j) {
        int s = csr[j];
        const float4* p = (const float4*)(hs + (size_t)s * 12);
#pragma unroll
        for (int q = 0; q < 3; ++q) {
            float4 v = p[q];
            acc[4 * q] += v.x; acc[4 * q + 1] += v.y; acc[4 * q + 2] += v.z; acc[4 * q + 3] += v.w;
        }
    }
    float di = dinv[i];
    float* o = out + (size_t)i * 12;
#pragma unroll
    for (int c = 0; c < 12; ++c)
        o[c] = (c < CC) ? fmaxf(di * acc[c] + bias[c], 0.f) : 0.f;
}

// ========== pool ==========
__global__ __launch_bounds__(256) void k_bounds(const int* __restrict__ batch,
                                                int* __restrict__ bounds) {
    int g = blockIdx.x * 256 + threadIdx.x;
    if (g > GG) return;
    int lo = 0, hi = NN;
    while (lo < hi) {
        int mid = (lo + hi) >> 1;
        if (batch[mid] < g) lo = mid + 1; else hi = mid;
    }
    bounds[g] = lo;
}

__global__ __launch_bounds__(256) void k_pool(const float* __restrict__ h,
                                              const int* __restrict__ bounds,
                                              float* __restrict__ out) {
    int g = blockIdx.x;
    int s = bounds[g], e = bounds[g + 1];
    float acc[CC];
#pragma unroll
    for (int c = 0; c < CC; ++c) acc[c] = 0.f;
    for (int i = s + threadIdx.x; i < e; i += 256) {
#pragma unroll
        for (int c = 0; c < CC; ++c) acc[c] += h[(size_t)i * 12 + c];
    }
#pragma unroll
    for (int off = 32; off >= 1; off >>= 1)
#pragma unroll
        for (int c = 0; c < CC; ++c) acc[c] += __shfl_down(acc[c], off, 64);
    __shared__ float sacc[4][CC];
    int wv = threadIdx.x >> 6, lane = threadIdx.x & 63;
    if (lane == 0) {
#pragma unroll
        for (int c = 0; c < CC; ++c) sacc[wv][c] = acc[c];
    }
    __syncthreads();
    if (threadIdx.x == 0) {
        float cnt = fmaxf((float)(e - s), 1.0f);
        float tot[CC];
        float m = -1e30f;
#pragma unroll
        for (int c = 0; c < CC; ++c) {
            tot[c] = (sacc[0][c] + sacc[1][c] + sacc[2][c] + sacc[3][c]) / cnt;
            m = fmaxf(m, tot[c]);
        }
        float ssum = 0.f;
#pragma unroll
        for (int c = 0; c < CC; ++c) ssum += expf(tot[c] - m);
        float lse = logf(ssum) + m;
#pragma unroll
        for (int c = 0; c < CC; ++c) out[(size_t)g * CC + c] = tot[c] - lse;
    }
}

extern "C" void kernel_launch(void* const* d_in, const int* in_sizes, int n_in,
                              void* d_out, int out_size, void* d_ws, size_t ws_size,
                              hipStream_t stream) {
    const float* x     = (const float*)d_in[0];
    const int*   ei    = (const int*)d_in[1];
    const int*   batch = (const int*)d_in[2];
    const float* W1 = (const float*)d_in[3];
    const float* b1 = (const float*)d_in[4];
    const float* W2 = (const float*)d_in[5];
    const float* b2 = (const float*)d_in[6];
    const float* W3 = (const float*)d_in[7];
    const float* b3 = (const float*)d_in[8];
    const float* W4 = (const float*)d_in[9];
    const float* b4 = (const float*)d_in[10];
    const float* Wf = (const float*)d_in[11];
    const float* bf = (const float*)d_in[12];
    float* out = (float*)d_out;

    const int* src = ei;
    const int* dst = ei + EE;

    // -------- workspace layout (4B units) --------
    int*   iw     = (int*)d_ws;
    int*   csr    = iw;                       // [3,200,000]
    int*   rowptr = csr + 3200000;            // [100,352]
    int*   counts = rowptr + 100352;          // [100,352]
    float* dinv   = (float*)(counts + 100352);// [100,352]
    int*   bhist  = (int*)(dinv + 100352);    // [256]
    int*   bbase  = bhist + 256;              // [256]
    int*   gcur   = bbase + 256;              // [256]
    int*   bounds = gcur + 256;               // [640]
    int*   part   = bounds + 640;             // [3,200,000] (overlaid by bufA/bufB later)
    float* bufA   = (float*)part;             // [1,200,128]
    float* bufB   = bufA + 1200128;           // [1,200,128]

    const int TB = (EE + 8191) / 8192;        // 391 partition tiles
    const int NB = (NN + 255) / 256;          // 391

    // -------- CSR build: bucketed counting sort --------
    hipMemsetAsync(bhist, 0, NBUCK * sizeof(int), stream);
    k_phist<<<TB, 256, 0, stream>>>(dst, bhist);
    k_scanb<<<1, 256, 0, stream>>>(bhist, bbase, gcur);
    k_partition<<<TB, 256, 0, stream>>>(src, dst, gcur, part);
    k_bucketfill<<<NBUCK, 512, 0, stream>>>(bbase, part, csr, rowptr, counts, dinv);

    // -------- layers (mm fused into gather epilogue) --------
    k_xw1<<<NN / 4, 256, 0, stream>>>(x, W1, dinv, bufA);                       // hs1 -> A
    k_gf<HH, 8><<<NB, 256, 0, stream>>>(rowptr, counts, csr, dinv, bufA, b1, W2, bufB);   // hs2 -> B
    k_gf<HH, 8><<<NB, 256, 0, stream>>>(rowptr, counts, csr, dinv, bufB, b2, W3, bufA);   // hs3 -> A
    k_gf<HH, 8><<<NB, 256, 0, stream>>>(rowptr, counts, csr, dinv, bufA, b3, W4, bufB);   // hs4 -> B
    k_gf<CC, 12><<<NB, 256, 0, stream>>>(rowptr, counts, csr, dinv, bufB, b4, Wf, bufA);  // hs5 -> A (12-pad)
    k_glast<<<NB, 256, 0, stream>>>(rowptr, counts, csr, dinv, bufA, bf, bufB);           // h5 -> B (12-pad)

    // -------- pool + log_softmax --------
    k_bounds<<<3, 256, 0, stream>>>(batch, bounds);
    k_pool<<<GG, 256, 0, stream>>>(bufB, bounds, out);
}

// Round 4
// 245.916 us; speedup vs baseline: 23.2255x; 1.4842x over previous
//
#include <hip/hip_runtime.h>
#include <math.h>

#define NN 100000
#define EE 3200000
#define FF 128
#define HH 6
#define CC 10
#define GG 512
#define NBUCK 196          // ceil(NN/512); bucket = dst >> 9
#define BCAP 20000         // per-bucket edge capacity (mean 16327, sigma 128)

typedef _Float16 half8 __attribute__((ext_vector_type(8)));

// ========== init per-bucket cursors to fixed bases ==========
__global__ __launch_bounds__(256) void k_initcur(int* __restrict__ gcur) {
    int t = threadIdx.x;
    if (t < NBUCK) gcur[t] = t * BCAP;
}

// ========== partition packed edges into bucket runs (fixed capacity) ==========
__global__ __launch_bounds__(256) void k_partition(const int* __restrict__ src,
                                                   const int* __restrict__ dst,
                                                   int* __restrict__ gcur,
                                                   int* __restrict__ part) {
    __shared__ int lcnt[NBUCK], lbase[NBUCK], lpos[NBUCK];
    int t = threadIdx.x;
    for (int i = t; i < NBUCK; i += 256) { lcnt[i] = 0; lpos[i] = 0; }
    __syncthreads();
    int base = blockIdx.x * 8192;
    for (int k = 0; k < 32; ++k) {
        int e = base + (k << 8) + t;
        if (e < EE) atomicAdd(&lcnt[dst[e] >> 9], 1);
    }
    __syncthreads();
    for (int i = t; i < NBUCK; i += 256)
        lbase[i] = lcnt[i] ? atomicAdd(&gcur[i], lcnt[i]) : 0;
    __syncthreads();
    for (int k = 0; k < 32; ++k) {
        int e = base + (k << 8) + t;
        if (e < EE) {
            int d = dst[e], bkt = d >> 9;
            int r = atomicAdd(&lpos[bkt], 1);
            part[lbase[bkt] + r] = (src[e] << 9) | (d & 511);
        }
    }
}

// ========== per-bucket counting sort -> csr (bucket-strided), rowptr, counts, dinv ==========
__global__ __launch_bounds__(512) void k_bucketfill(const int* __restrict__ gcur,
                                                    const int* __restrict__ part,
                                                    int* __restrict__ csr,
                                                    int* __restrict__ rowptr,
                                                    int* __restrict__ counts,
                                                    float* __restrict__ dinv) {
    __shared__ int cnt[512], scn[512], cur[512];
    int t = threadIdx.x;
    int b = blockIdx.x;
    int nbase = b << 9;
    int ebase = b * BCAP, ecount = gcur[b] - ebase;
    cnt[t] = 0;
    __syncthreads();
    for (int j = t; j < ecount; j += 512)
        atomicAdd(&cnt[part[ebase + j] & 511], 1);
    __syncthreads();
    int c = cnt[t];
    scn[t] = c;
    __syncthreads();
    for (int off = 1; off < 512; off <<= 1) {
        int u = (t >= off) ? scn[t - off] : 0;
        __syncthreads();
        scn[t] += u;
        __syncthreads();
    }
    int rp = ebase + scn[t] - c;   // exclusive within bucket, bucket-strided
    int node = nbase + t;
    if (node < NN) {
        rowptr[node] = rp;
        counts[node] = c;
        dinv[node] = rsqrtf((float)c + 1.0f);
    }
    cur[t] = rp;
    __syncthreads();
    for (int j = t; j < ecount; j += 512) {
        int p = part[ebase + j];
        int pos = atomicAdd(&cur[p & 511], 1);
        csr[pos] = p >> 9;
    }
}

// ========== layer 1: hs = dinv * (x @ W1) -> half, 8-pad ==========
__global__ __launch_bounds__(256) void k_xw1(const float* __restrict__ x,
                                             const float* __restrict__ W,
                                             const float* __restrict__ dinv,
                                             _Float16* __restrict__ hs) {
    __shared__ float sW[FF * HH];
    for (int i = threadIdx.x; i < FF * HH; i += 256) sW[i] = W[i];
    __syncthreads();
    int wid  = (blockIdx.x * 256 + threadIdx.x) >> 6;
    int lane = threadIdx.x & 63;
    if (wid >= NN) return;
    const float* xr = x + (size_t)wid * FF;
    float a0 = xr[lane], a1 = xr[lane + 64];
    float acc[HH];
#pragma unroll
    for (int c = 0; c < HH; ++c)
        acc[c] = a0 * sW[lane * HH + c] + a1 * sW[(lane + 64) * HH + c];
#pragma unroll
    for (int off = 32; off >= 1; off >>= 1)
#pragma unroll
        for (int c = 0; c < HH; ++c) acc[c] += __shfl_down(acc[c], off, 64);
    if (lane == 0) {
        float di = dinv[wid];
        half8 o;
#pragma unroll
        for (int c = 0; c < HH; ++c) o[c] = (_Float16)(di * acc[c]);
        o[6] = (_Float16)0.f; o[7] = (_Float16)0.f;
        *((half8*)(hs + (size_t)wid * 8)) = o;
    }
}

// ===== fused gather + next mm, 4 lanes per node =====
// h = relu(dinv*(sum_nbr hs + hs_self) + b); out = dinv*(h @ Wn), HPOH halves pad
template <int HON, int HPOH>
__global__ __launch_bounds__(256) void k_gf(const int* __restrict__ rowptr,
                                            const int* __restrict__ counts,
                                            const int* __restrict__ csr,
                                            const float* __restrict__ dinv,
                                            const _Float16* __restrict__ hs,
                                            const float* __restrict__ bias,
                                            const float* __restrict__ Wn,
                                            _Float16* __restrict__ outn) {
    __shared__ float sW[HH * HON];
    if (threadIdx.x < HH * HON) sW[threadIdx.x] = Wn[threadIdx.x];
    __syncthreads();
    int node = blockIdx.x * 64 + (threadIdx.x >> 2);
    int sub  = threadIdx.x & 3;
    if (node >= NN) return;
    int st = rowptr[node], cnt = counts[node];
    float a[HH];
    if (sub == 0) {
        half8 v = *((const half8*)(hs + (size_t)node * 8));
#pragma unroll
        for (int c = 0; c < HH; ++c) a[c] = (float)v[c];
    } else {
#pragma unroll
        for (int c = 0; c < HH; ++c) a[c] = 0.f;
    }
    int j = st + sub, end = st + cnt;
    for (; j + 4 < end; j += 8) {
        int s0 = csr[j], s1 = csr[j + 4];
        half8 v0 = *((const half8*)(hs + (size_t)s0 * 8));
        half8 v1 = *((const half8*)(hs + (size_t)s1 * 8));
#pragma unroll
        for (int c = 0; c < HH; ++c) a[c] += (float)v0[c] + (float)v1[c];
    }
    if (j < end) {
        int s = csr[j];
        half8 v = *((const half8*)(hs + (size_t)s * 8));
#pragma unroll
        for (int c = 0; c < HH; ++c) a[c] += (float)v[c];
    }
#pragma unroll
    for (int c = 0; c < HH; ++c) {
        a[c] += __shfl_xor(a[c], 1, 64);
        a[c] += __shfl_xor(a[c], 2, 64);
    }
    if (sub == 0) {
        float di = dinv[node];
        float h[HH];
#pragma unroll
        for (int c = 0; c < HH; ++c) h[c] = fmaxf(di * a[c] + bias[c], 0.f);
        half8 o[HPOH / 8];
#pragma unroll
        for (int c = 0; c < HPOH; ++c) {
            float s = 0.f;
            if (c < HON) {
#pragma unroll
                for (int k = 0; k < HH; ++k) s += h[k] * sW[k * HON + c];
                o[c / 8][c % 8] = (_Float16)(di * s);
            } else {
                o[c / 8][c % 8] = (_Float16)0.f;
            }
        }
        half8* op = (half8*)(outn + (size_t)node * HPOH);
#pragma unroll
        for (int q = 0; q < HPOH / 8; ++q) op[q] = o[q];
    }
}

// ===== last gather: h5 = relu(dinv*(sum hs5 + self) + bf) -> f32 12-pad =====
__global__ __launch_bounds__(256) void k_glast(const int* __restrict__ rowptr,
                                               const int* __restrict__ counts,
                                               const int* __restrict__ csr,
                                               const float* __restrict__ dinv,
                                               const _Float16* __restrict__ hs,
                                               const float* __restrict__ bias,
                                               float* __restrict__ out) {
    int node = blockIdx.x * 64 + (threadIdx.x >> 2);
    int sub  = threadIdx.x & 3;
    if (node >= NN) return;
    int st = rowptr[node], cnt = counts[node];
    float a[CC];
    if (sub == 0) {
        const half8* p = (const half8*)(hs + (size_t)node * 16);
        half8 v0 = p[0], v1 = p[1];
#pragma unroll
        for (int c = 0; c < 8; ++c) a[c] = (float)v0[c];
        a[8] = (float)v1[0]; a[9] = (float)v1[1];
    } else {
#pragma unroll
        for (int c = 0; c < CC; ++c) a[c] = 0.f;
    }
    int j = st + sub, end = st + cnt;
    for (; j + 4 < end; j += 8) {
        int s0 = csr[j], s1 = csr[j + 4];
        const half8* p0 = (const half8*)(hs + (size_t)s0 * 16);
        const half8* p1 = (const half8*)(hs + (size_t)s1 * 16);
        half8 x0 = p0[0], y0 = p0[1], x1 = p1[0], y1 = p1[1];
#pragma unroll
        for (int c = 0; c < 8; ++c) a[c] += (float)x0[c] + (float)x1[c];
        a[8] += (float)y0[0] + (float)y1[0];
        a[9] += (float)y0[1] + (float)y1[1];
    }
    if (j < end) {
        int s = csr[j];
        const half8* p = (const half8*)(hs + (size_t)s * 16);
        half8 x0 = p[0], y0 = p[1];
#pragma unroll
        for (int c = 0; c < 8; ++c) a[c] += (float)x0[c];
        a[8] += (float)y0[0]; a[9] += (float)y0[1];
    }
#pragma unroll
    for (int c = 0; c < CC; ++c) {
        a[c] += __shfl_xor(a[c], 1, 64);
        a[c] += __shfl_xor(a[c], 2, 64);
    }
    if (sub == 0) {
        float di = dinv[node];
        float r[12];
#pragma unroll
        for (int c = 0; c < 12; ++c)
            r[c] = (c < CC) ? fmaxf(di * a[c] + bias[c], 0.f) : 0.f;
        float4* o = (float4*)(out + (size_t)node * 12);
        o[0] = make_float4(r[0], r[1], r[2], r[3]);
        o[1] = make_float4(r[4], r[5], r[6], r[7]);
        o[2] = make_float4(r[8], r[9], r[10], r[11]);
    }
}

// ========== pool ==========
__global__ __launch_bounds__(256) void k_bounds(const int* __restrict__ batch,
                                                int* __restrict__ bounds) {
    int g = blockIdx.x * 256 + threadIdx.x;
    if (g > GG) return;
    int lo = 0, hi = NN;
    while (lo < hi) {
        int mid = (lo + hi) >> 1;
        if (batch[mid] < g) lo = mid + 1; else hi = mid;
    }
    bounds[g] = lo;
}

__global__ __launch_bounds__(256) void k_pool(const float* __restrict__ h,
                                              const int* __restrict__ bounds,
                                              float* __restrict__ out) {
    int g = blockIdx.x;
    int s = bounds[g], e = bounds[g + 1];
    float acc[CC];
#pragma unroll
    for (int c = 0; c < CC; ++c) acc[c] = 0.f;
    for (int i = s + threadIdx.x; i < e; i += 256) {
#pragma unroll
        for (int c = 0; c < CC; ++c) acc[c] += h[(size_t)i * 12 + c];
    }
#pragma unroll
    for (int off = 32; off >= 1; off >>= 1)
#pragma unroll
        for (int c = 0; c < CC; ++c) acc[c] += __shfl_down(acc[c], off, 64);
    __shared__ float sacc[4][CC];
    int wv = threadIdx.x >> 6, lane = threadIdx.x & 63;
    if (lane == 0) {
#pragma unroll
        for (int c = 0; c < CC; ++c) sacc[wv][c] = acc[c];
    }
    __syncthreads();
    if (threadIdx.x == 0) {
        float cnt = fmaxf((float)(e - s), 1.0f);
        float tot[CC];
        float m = -1e30f;
#pragma unroll
        for (int c = 0; c < CC; ++c) {
            tot[c] = (sacc[0][c] + sacc[1][c] + sacc[2][c] + sacc[3][c]) / cnt;
            m = fmaxf(m, tot[c]);
        }
        float ssum = 0.f;
#pragma unroll
        for (int c = 0; c < CC; ++c) ssum += expf(tot[c] - m);
        float lse = logf(ssum) + m;
#pragma unroll
        for (int c = 0; c < CC; ++c) out[(size_t)g * CC + c] = tot[c] - lse;
    }
}

extern "C" void kernel_launch(void* const* d_in, const int* in_sizes, int n_in,
                              void* d_out, int out_size, void* d_ws, size_t ws_size,
                              hipStream_t stream) {
    const float* x     = (const float*)d_in[0];
    const int*   ei    = (const int*)d_in[1];
    const int*   batch = (const int*)d_in[2];
    const float* W1 = (const float*)d_in[3];
    const float* b1 = (const float*)d_in[4];
    const float* W2 = (const float*)d_in[5];
    const float* b2 = (const float*)d_in[6];
    const float* W3 = (const float*)d_in[7];
    const float* b3 = (const float*)d_in[8];
    const float* W4 = (const float*)d_in[9];
    const float* b4 = (const float*)d_in[10];
    const float* Wf = (const float*)d_in[11];
    const float* bf = (const float*)d_in[12];
    float* out = (float*)d_out;

    const int* src = ei;
    const int* dst = ei + EE;

    // -------- workspace layout (4B units) --------
    int*   iw     = (int*)d_ws;
    int*   csr    = iw;                        // [3,920,000] bucket-strided
    int*   rowptr = csr + 3920000;             // [100,352]
    int*   counts = rowptr + 100352;           // [100,352]
    float* dinv   = (float*)(counts + 100352); // [100,352]
    int*   gcur   = (int*)(dinv + 100352);     // [256]
    int*   bounds = gcur + 256;                // [640]
    int*   part   = bounds + 640;              // [3,920,000], overlaid after bucketfill:
    _Float16* hsA = (_Float16*)part;           //   [1,605,632 halves]
    _Float16* hsB = hsA + 1605632;             //   [1,605,632 halves]
    float* h5     = (float*)(hsB + 1605632);   //   [1,204,224 floats]

    const int TB = (EE + 8191) / 8192;         // 391
    const int GB = (NN + 63) / 64;             // 1563 (4 lanes per node)

    // -------- CSR build --------
    k_initcur<<<1, 256, 0, stream>>>(gcur);
    k_partition<<<TB, 256, 0, stream>>>(src, dst, gcur, part);
    k_bucketfill<<<NBUCK, 512, 0, stream>>>(gcur, part, csr, rowptr, counts, dinv);

    // -------- layers --------
    k_xw1<<<NN / 4, 256, 0, stream>>>(x, W1, dinv, hsA);                                   // hs1
    k_gf<HH, 8><<<GB, 256, 0, stream>>>(rowptr, counts, csr, dinv, hsA, b1, W2, hsB);      // hs2
    k_gf<HH, 8><<<GB, 256, 0, stream>>>(rowptr, counts, csr, dinv, hsB, b2, W3, hsA);      // hs3
    k_gf<HH, 8><<<GB, 256, 0, stream>>>(rowptr, counts, csr, dinv, hsA, b3, W4, hsB);      // hs4
    k_gf<CC, 16><<<GB, 256, 0, stream>>>(rowptr, counts, csr, dinv, hsB, b4, Wf, hsA);     // hs5 (16-pad)
    k_glast<<<GB, 256, 0, stream>>>(rowptr, counts, csr, dinv, hsA, bf, h5);               // h5 f32

    // -------- pool + log_softmax --------
    k_bounds<<<3, 256, 0, stream>>>(batch, bounds);
    k_pool<<<GG, 256, 0, stream>>>(h5, bounds, out);
}

// Round 5
// 223.507 us; speedup vs baseline: 25.5541x; 1.1003x over previous
//
#include <hip/hip_runtime.h>
#include <math.h>

#define NN 100000
#define EE 3200000
#define FF 128
#define HH 6
#define CC 10
#define GG 512
#define NBUCK 196          // ceil(NN/512); bucket = dst >> 9
#define BCAP 20000         // per-bucket edge capacity (mean 16327, sigma 128)
#define PTILE 4096

typedef _Float16 half8 __attribute__((ext_vector_type(8)));

// ========== init per-bucket cursors to fixed bases ==========
__global__ __launch_bounds__(256) void k_initcur(int* __restrict__ gcur) {
    int t = threadIdx.x;
    if (t < NBUCK) gcur[t] = t * BCAP;
}

// ========== partition packed edges into bucket runs (fixed capacity) ==========
__global__ __launch_bounds__(256) void k_partition(const int* __restrict__ src,
                                                   const int* __restrict__ dst,
                                                   int* __restrict__ gcur,
                                                   int* __restrict__ part) {
    __shared__ int lcnt[NBUCK], lbase[NBUCK], lpos[NBUCK];
    int t = threadIdx.x;
    for (int i = t; i < NBUCK; i += 256) { lcnt[i] = 0; lpos[i] = 0; }
    __syncthreads();
    int base = blockIdx.x * PTILE;
    int d[16];
#pragma unroll
    for (int k = 0; k < 16; ++k) {
        int e = base + (k << 8) + t;
        d[k] = (e < EE) ? dst[e] : -1;
    }
#pragma unroll
    for (int k = 0; k < 16; ++k)
        if (d[k] >= 0) atomicAdd(&lcnt[d[k] >> 9], 1);
    __syncthreads();
    for (int i = t; i < NBUCK; i += 256)
        lbase[i] = lcnt[i] ? atomicAdd(&gcur[i], lcnt[i]) : 0;
    __syncthreads();
    int s[16];
#pragma unroll
    for (int k = 0; k < 16; ++k) {
        int e = base + (k << 8) + t;
        s[k] = (e < EE) ? src[e] : 0;
    }
#pragma unroll
    for (int k = 0; k < 16; ++k) {
        if (d[k] >= 0) {
            int bkt = d[k] >> 9;
            int r = atomicAdd(&lpos[bkt], 1);
            part[lbase[bkt] + r] = (s[k] << 9) | (d[k] & 511);
        }
    }
}

// ========== per-bucket counting sort -> csr (bucket-strided), rowptr, counts, dinv ==========
__global__ __launch_bounds__(512) void k_bucketfill(const int* __restrict__ gcur,
                                                    const int* __restrict__ part,
                                                    int* __restrict__ csr,
                                                    int* __restrict__ rowptr,
                                                    int* __restrict__ counts,
                                                    float* __restrict__ dinv) {
    __shared__ int cnt[512], scn[512], cur[512];
    int t = threadIdx.x;
    int b = blockIdx.x;
    int nbase = b << 9;
    int ebase = b * BCAP, ecount = gcur[b] - ebase;
    cnt[t] = 0;
    __syncthreads();
    for (int j = t; j < ecount; j += 512)
        atomicAdd(&cnt[part[ebase + j] & 511], 1);
    __syncthreads();
    int c = cnt[t];
    scn[t] = c;
    __syncthreads();
    for (int off = 1; off < 512; off <<= 1) {
        int u = (t >= off) ? scn[t - off] : 0;
        __syncthreads();
        scn[t] += u;
        __syncthreads();
    }
    int rp = ebase + scn[t] - c;   // exclusive within bucket, bucket-strided
    int node = nbase + t;
    if (node < NN) {
        rowptr[node] = rp;
        counts[node] = c;
        dinv[node] = rsqrtf((float)c + 1.0f);
    }
    cur[t] = rp;
    __syncthreads();
    for (int j = t; j < ecount; j += 512) {
        int p = part[ebase + j];
        int pos = atomicAdd(&cur[p & 511], 1);
        csr[pos] = p >> 9;
    }
}

// ========== layer 1: hs = dinv * (x @ W1) -> half, 8-pad; 4 lanes per node ==========
__global__ __launch_bounds__(256) void k_xw1(const float* __restrict__ x,
                                             const float* __restrict__ W,
                                             const float* __restrict__ dinv,
                                             _Float16* __restrict__ hs) {
    __shared__ float sW[FF * HH];
    for (int i = threadIdx.x; i < FF * HH; i += 256) sW[i] = W[i];
    __syncthreads();
    int node = blockIdx.x * 64 + (threadIdx.x >> 2);
    int sub  = threadIdx.x & 3;
    if (node >= NN) return;
    const float4* xr = (const float4*)(x + (size_t)node * FF + sub * 32);
    float acc[HH];
#pragma unroll
    for (int c = 0; c < HH; ++c) acc[c] = 0.f;
#pragma unroll
    for (int q = 0; q < 8; ++q) {
        float4 v = xr[q];
        int k = sub * 32 + q * 4;
        const float* w0 = &sW[(k + 0) * HH];
        const float* w1 = &sW[(k + 1) * HH];
        const float* w2 = &sW[(k + 2) * HH];
        const float* w3 = &sW[(k + 3) * HH];
#pragma unroll
        for (int c = 0; c < HH; ++c)
            acc[c] += v.x * w0[c] + v.y * w1[c] + v.z * w2[c] + v.w * w3[c];
    }
#pragma unroll
    for (int c = 0; c < HH; ++c) {
        acc[c] += __shfl_xor(acc[c], 1, 64);
        acc[c] += __shfl_xor(acc[c], 2, 64);
    }
    if (sub == 0) {
        float di = dinv[node];
        half8 o;
#pragma unroll
        for (int c = 0; c < HH; ++c) o[c] = (_Float16)(di * acc[c]);
        o[6] = (_Float16)0.f; o[7] = (_Float16)0.f;
        *((half8*)(hs + (size_t)node * 8)) = o;
    }
}

// ===== fused gather + next mm, 4 lanes per node =====
template <int HON, int HPOH>
__global__ __launch_bounds__(256) void k_gf(const int* __restrict__ rowptr,
                                            const int* __restrict__ counts,
                                            const int* __restrict__ csr,
                                            const float* __restrict__ dinv,
                                            const _Float16* __restrict__ hs,
                                            const float* __restrict__ bias,
                                            const float* __restrict__ Wn,
                                            _Float16* __restrict__ outn) {
    __shared__ float sW[HH * HON];
    if (threadIdx.x < HH * HON) sW[threadIdx.x] = Wn[threadIdx.x];
    __syncthreads();
    int node = blockIdx.x * 64 + (threadIdx.x >> 2);
    int sub  = threadIdx.x & 3;
    if (node >= NN) return;
    int st = rowptr[node], cnt = counts[node];
    float a[HH];
    if (sub == 0) {
        half8 v = *((const half8*)(hs + (size_t)node * 8));
#pragma unroll
        for (int c = 0; c < HH; ++c) a[c] = (float)v[c];
    } else {
#pragma unroll
        for (int c = 0; c < HH; ++c) a[c] = 0.f;
    }
    int j = st + sub, end = st + cnt;
    for (; j + 4 < end; j += 8) {
        int s0 = csr[j], s1 = csr[j + 4];
        half8 v0 = *((const half8*)(hs + (size_t)s0 * 8));
        half8 v1 = *((const half8*)(hs + (size_t)s1 * 8));
#pragma unroll
        for (int c = 0; c < HH; ++c) a[c] += (float)v0[c] + (float)v1[c];
    }
    if (j < end) {
        int s = csr[j];
        half8 v = *((const half8*)(hs + (size_t)s * 8));
#pragma unroll
        for (int c = 0; c < HH; ++c) a[c] += (float)v[c];
    }
#pragma unroll
    for (int c = 0; c < HH; ++c) {
        a[c] += __shfl_xor(a[c], 1, 64);
        a[c] += __shfl_xor(a[c], 2, 64);
    }
    if (sub == 0) {
        float di = dinv[node];
        float h[HH];
#pragma unroll
        for (int c = 0; c < HH; ++c) h[c] = fmaxf(di * a[c] + bias[c], 0.f);
        half8 o[HPOH / 8];
#pragma unroll
        for (int c = 0; c < HPOH; ++c) {
            float s = 0.f;
            if (c < HON) {
#pragma unroll
                for (int k = 0; k < HH; ++k) s += h[k] * sW[k * HON + c];
                o[c / 8][c % 8] = (_Float16)(di * s);
            } else {
                o[c / 8][c % 8] = (_Float16)0.f;
            }
        }
        half8* op = (half8*)(outn + (size_t)node * HPOH);
#pragma unroll
        for (int q = 0; q < HPOH / 8; ++q) op[q] = o[q];
    }
}

// ===== last gather: h5 = relu(dinv*(sum hs5 + self) + bf) -> f32 12-pad =====
__global__ __launch_bounds__(256) void k_glast(const int* __restrict__ rowptr,
                                               const int* __restrict__ counts,
                                               const int* __restrict__ csr,
                                               const float* __restrict__ dinv,
                                               const _Float16* __restrict__ hs,
                                               const float* __restrict__ bias,
                                               float* __restrict__ out) {
    int node = blockIdx.x * 64 + (threadIdx.x >> 2);
    int sub  = threadIdx.x & 3;
    if (node >= NN) return;
    int st = rowptr[node], cnt = counts[node];
    float a[CC];
    if (sub == 0) {
        const half8* p = (const half8*)(hs + (size_t)node * 16);
        half8 v0 = p[0], v1 = p[1];
#pragma unroll
        for (int c = 0; c < 8; ++c) a[c] = (float)v0[c];
        a[8] = (float)v1[0]; a[9] = (float)v1[1];
    } else {
#pragma unroll
        for (int c = 0; c < CC; ++c) a[c] = 0.f;
    }
    int j = st + sub, end = st + cnt;
    for (; j + 4 < end; j += 8) {
        int s0 = csr[j], s1 = csr[j + 4];
        const half8* p0 = (const half8*)(hs + (size_t)s0 * 16);
        const half8* p1 = (const half8*)(hs + (size_t)s1 * 16);
        half8 x0 = p0[0], y0 = p0[1], x1 = p1[0], y1 = p1[1];
#pragma unroll
        for (int c = 0; c < 8; ++c) a[c] += (float)x0[c] + (float)x1[c];
        a[8] += (float)y0[0] + (float)y1[0];
        a[9] += (float)y0[1] + (float)y1[1];
    }
    if (j < end) {
        int s = csr[j];
        const half8* p = (const half8*)(hs + (size_t)s * 16);
        half8 x0 = p[0], y0 = p[1];
#pragma unroll
        for (int c = 0; c < 8; ++c) a[c] += (float)x0[c];
        a[8] += (float)y0[0]; a[9] += (float)y0[1];
    }
#pragma unroll
    for (int c = 0; c < CC; ++c) {
        a[c] += __shfl_xor(a[c], 1, 64);
        a[c] += __shfl_xor(a[c], 2, 64);
    }
    if (sub == 0) {
        float di = dinv[node];
        float r[12];
#pragma unroll
        for (int c = 0; c < 12; ++c)
            r[c] = (c < CC) ? fmaxf(di * a[c] + bias[c], 0.f) : 0.f;
        float4* o = (float4*)(out + (size_t)node * 12);
        o[0] = make_float4(r[0], r[1], r[2], r[3]);
        o[1] = make_float4(r[4], r[5], r[6], r[7]);
        o[2] = make_float4(r[8], r[9], r[10], r[11]);
    }
}

// ========== pool ==========
__global__ __launch_bounds__(256) void k_bounds(const int* __restrict__ batch,
                                                int* __restrict__ bounds) {
    int g = blockIdx.x * 256 + threadIdx.x;
    if (g > GG) return;
    int lo = 0, hi = NN;
    while (lo < hi) {
        int mid = (lo + hi) >> 1;
        if (batch[mid] < g) lo = mid + 1; else hi = mid;
    }
    bounds[g] = lo;
}

__global__ __launch_bounds__(256) void k_pool(const float* __restrict__ h,
                                              const int* __restrict__ bounds,
                                              float* __restrict__ out) {
    int g = blockIdx.x;
    int s = bounds[g], e = bounds[g + 1];
    float acc[CC];
#pragma unroll
    for (int c = 0; c < CC; ++c) acc[c] = 0.f;
    for (int i = s + threadIdx.x; i < e; i += 256) {
#pragma unroll
        for (int c = 0; c < CC; ++c) acc[c] += h[(size_t)i * 12 + c];
    }
#pragma unroll
    for (int off = 32; off >= 1; off >>= 1)
#pragma unroll
        for (int c = 0; c < CC; ++c) acc[c] += __shfl_down(acc[c], off, 64);
    __shared__ float sacc[4][CC];
    int wv = threadIdx.x >> 6, lane = threadIdx.x & 63;
    if (lane == 0) {
#pragma unroll
        for (int c = 0; c < CC; ++c) sacc[wv][c] = acc[c];
    }
    __syncthreads();
    if (threadIdx.x == 0) {
        float cnt = fmaxf((float)(e - s), 1.0f);
        float tot[CC];
        float m = -1e30f;
#pragma unroll
        for (int c = 0; c < CC; ++c) {
            tot[c] = (sacc[0][c] + sacc[1][c] + sacc[2][c] + sacc[3][c]) / cnt;
            m = fmaxf(m, tot[c]);
        }
        float ssum = 0.f;
#pragma unroll
        for (int c = 0; c < CC; ++c) ssum += expf(tot[c] - m);
        float lse = logf(ssum) + m;
#pragma unroll
        for (int c = 0; c < CC; ++c) out[(size_t)g * CC + c] = tot[c] - lse;
    }
}

extern "C" void kernel_launch(void* const* d_in, const int* in_sizes, int n_in,
                              void* d_out, int out_size, void* d_ws, size_t ws_size,
                              hipStream_t stream) {
    const float* x     = (const float*)d_in[0];
    const int*   ei    = (const int*)d_in[1];
    const int*   batch = (const int*)d_in[2];
    const float* W1 = (const float*)d_in[3];
    const float* b1 = (const float*)d_in[4];
    const float* W2 = (const float*)d_in[5];
    const float* b2 = (const float*)d_in[6];
    const float* W3 = (const float*)d_in[7];
    const float* b3 = (const float*)d_in[8];
    const float* W4 = (const float*)d_in[9];
    const float* b4 = (const float*)d_in[10];
    const float* Wf = (const float*)d_in[11];
    const float* bf = (const float*)d_in[12];
    float* out = (float*)d_out;

    const int* src = ei;
    const int* dst = ei + EE;

    // -------- workspace layout (4B units) --------
    int*   iw     = (int*)d_ws;
    int*   csr    = iw;                        // [3,920,000] bucket-strided
    int*   rowptr = csr + 3920000;             // [100,352]
    int*   counts = rowptr + 100352;           // [100,352]
    float* dinv   = (float*)(counts + 100352); // [100,352]
    int*   gcur   = (int*)(dinv + 100352);     // [256]
    int*   bounds = gcur + 256;                // [640]
    int*   part   = bounds + 640;              // [3,920,000], overlaid after bucketfill:
    _Float16* hsA = (_Float16*)part;           //   [1,605,632 halves]
    _Float16* hsB = hsA + 1605632;             //   [1,605,632 halves]
    float* h5     = (float*)(hsB + 1605632);   //   [1,204,224 floats]

    const int TB = (EE + PTILE - 1) / PTILE;   // 782
    const int GB = (NN + 63) / 64;             // 1563 (4 lanes per node)

    // -------- CSR build --------
    k_initcur<<<1, 256, 0, stream>>>(gcur);
    k_partition<<<TB, 256, 0, stream>>>(src, dst, gcur, part);
    k_bucketfill<<<NBUCK, 512, 0, stream>>>(gcur, part, csr, rowptr, counts, dinv);

    // -------- layers --------
    k_xw1<<<GB, 256, 0, stream>>>(x, W1, dinv, hsA);                                       // hs1
    k_gf<HH, 8><<<GB, 256, 0, stream>>>(rowptr, counts, csr, dinv, hsA, b1, W2, hsB);      // hs2
    k_gf<HH, 8><<<GB, 256, 0, stream>>>(rowptr, counts, csr, dinv, hsB, b2, W3, hsA);      // hs3
    k_gf<HH, 8><<<GB, 256, 0, stream>>>(rowptr, counts, csr, dinv, hsA, b3, W4, hsB);      // hs4
    k_gf<CC, 16><<<GB, 256, 0, stream>>>(rowptr, counts, csr, dinv, hsB, b4, Wf, hsA);     // hs5 (16-pad)
    k_glast<<<GB, 256, 0, stream>>>(rowptr, counts, csr, dinv, hsA, bf, h5);               // h5 f32

    // -------- pool + log_softmax --------
    k_bounds<<<3, 256, 0, stream>>>(batch, bounds);
    k_pool<<<GG, 256, 0, stream>>>(h5, bounds, out);
}